// Round 4
// baseline (554.879 us; speedup 1.0000x reference)
//
#include <hip/hip_runtime.h>

// EntNet: B=32, S=256, L=64, D=100, M=20
// K1 encode_k : contiguous-sweep row staging (products) into LDS, (l,c) reduce -> enc[8192,100]
// K2 project_k: sWp[r,e] = enc[r]·W[e,:], kg[r,m] = enc[r]·keys[m,:]
// K3 entnet_scan: 640 chains, 1 wave each, zero barriers, unnormalized-mem (rn folded as
//    wave-uniform scalar), 3-value fused DPP reduction, 5-way split matvec accumulators.

typedef float v2f __attribute__((ext_vector_type(2)));

__global__ __launch_bounds__(64) void encode_k(
    const float* __restrict__ batch,
    const float* __restrict__ encm,
    float* __restrict__ enc)
{
    __shared__ float4 stage[1600];   // one row of products (25.6 KB)
    __shared__ float4 part[50];
    const int lane = threadIdx.x;
    // encm flat [64*100] = 1600 float4, same layout as one batch row
    float4 MU[25];
    const float4* e4 = (const float4*)encm;
    #pragma unroll
    for (int i = 0; i < 25; ++i) MU[i] = e4[i * 64 + lane];
    const int q = (lane >= 25) ? 1 : 0;
    const int c = lane - 25 * q;
    const bool red = (lane < 50);

    for (int r8 = 0; r8 < 8; ++r8) {
        const int row = blockIdx.x * 8 + r8;
        const float4* rb = (const float4*)batch + (size_t)row * 1600;
        #pragma unroll
        for (int i = 0; i < 25; ++i) {            // contiguous 1 KB per instr
            float4 x = rb[i * 64 + lane];
            float4 mu = MU[i];
            float4 p;
            p.x = x.x * mu.x; p.y = x.y * mu.y; p.z = x.z * mu.z; p.w = x.w * mu.w;
            stage[i * 64 + lane] = p;
        }
        __syncthreads();
        float4 a0 = {0.f,0.f,0.f,0.f}, a1 = {0.f,0.f,0.f,0.f};
        if (red) {
            const int l0 = 32 * q;
            #pragma unroll
            for (int k = 0; k < 32; k += 2) {
                float4 u = stage[(l0 + k) * 25 + c];
                float4 v = stage[(l0 + k + 1) * 25 + c];
                a0.x += u.x; a0.y += u.y; a0.z += u.z; a0.w += u.w;
                a1.x += v.x; a1.y += v.y; a1.z += v.z; a1.w += v.w;
            }
            float4 s;
            s.x = a0.x + a1.x; s.y = a0.y + a1.y; s.z = a0.z + a1.z; s.w = a0.w + a1.w;
            part[lane] = s;
        }
        __syncthreads();
        if (lane < 25) {
            float4 s = part[lane], t2 = part[lane + 25];
            float4 o;
            o.x = s.x + t2.x; o.y = s.y + t2.y; o.z = s.z + t2.z; o.w = s.w + t2.w;
            ((float4*)enc)[(size_t)row * 25 + lane] = o;
        }
        __syncthreads();
    }
}

__global__ __launch_bounds__(128) void project_k(
    const float* __restrict__ enc,
    const float* __restrict__ W,
    const float* __restrict__ keys,
    float* __restrict__ sWp,
    float* __restrict__ kg)
{
    const int t = threadIdx.x;
    if (t >= 120) return;
    const float* wrow = (t < 100) ? (W + t * 100) : (keys + (t - 100) * 100);
    const int row0 = blockIdx.x * 4;                  // 2048 blocks -> 8192 rows
    const float4* w4 = (const float4*)wrow;
    const float4* e0 = (const float4*)(enc + (size_t)row0 * 100);
    const float4* e1 = e0 + 25;
    const float4* e2 = e0 + 50;
    const float4* e3 = e0 + 75;
    float a0 = 0.f, a1 = 0.f, a2 = 0.f, a3 = 0.f;
    #pragma unroll
    for (int k = 0; k < 25; ++k) {
        float4 w = w4[k];
        float4 s0 = e0[k], s1 = e1[k], s2 = e2[k], s3 = e3[k];
        a0 += w.x * s0.x + w.y * s0.y + w.z * s0.z + w.w * s0.w;
        a1 += w.x * s1.x + w.y * s1.y + w.z * s1.z + w.w * s1.w;
        a2 += w.x * s2.x + w.y * s2.y + w.z * s2.z + w.w * s2.w;
        a3 += w.x * s3.x + w.y * s3.y + w.z * s3.z + w.w * s3.w;
    }
    if (t < 100) {
        sWp[(size_t)row0 * 100 + t]       = a0;
        sWp[(size_t)(row0 + 1) * 100 + t] = a1;
        sWp[(size_t)(row0 + 2) * 100 + t] = a2;
        sWp[(size_t)(row0 + 3) * 100 + t] = a3;
    } else {
        const int m = t - 100;
        kg[(size_t)row0 * 20 + m]       = a0;
        kg[(size_t)(row0 + 1) * 20 + m] = a1;
        kg[(size_t)(row0 + 2) * 20 + m] = a2;
        kg[(size_t)(row0 + 3) * 20 + m] = a3;
    }
}

template <int CTRL>
__device__ __forceinline__ float dpp_add_f(float x) {
    int s = __builtin_amdgcn_update_dpp(0, __float_as_int(x), CTRL, 0xF, 0xF, true);
    return x + __int_as_float(s);
}
__device__ __forceinline__ float lane63(float x) {
    return __int_as_float(__builtin_amdgcn_readlane(__float_as_int(x), 63));
}

__global__ __launch_bounds__(64, 1) void entnet_scan(
    const float* __restrict__ enc,    // [8192*100]
    const float* __restrict__ sWp,    // [8192*100]
    const float* __restrict__ kg,     // [8192*20]
    const float* __restrict__ keys,   // [20*100]
    const float* __restrict__ U,      // [100*100]
    const float* __restrict__ V,      // [100*100]
    const float* __restrict__ paPtr,
    float* __restrict__ out)          // [32*20*100]
{
    __shared__ float4 mem4[32];       // 128 floats; [100..127] = masked-garbage zone
    float* memF = (float*)mem4;
    const int lane = threadIdx.x;
    const int b = blockIdx.x / 20;
    const int m = blockIdx.x % 20;
    const bool hi = (lane < 36);
    const float h = hi ? 1.f : 0.f;
    const int e0 = lane;
    const int e1 = hi ? (64 + lane) : 99;
    const float pa = paPtr[0];

    v2f Upk[100];
    {
        const float4* u0 = (const float4*)(U + e0 * 100);
        const float4* u1 = (const float4*)(U + e1 * 100);
        #pragma unroll
        for (int k = 0; k < 25; ++k) {
            float4 a = u0[k], c = u1[k];
            Upk[4 * k + 0] = (v2f){a.x, c.x};
            Upk[4 * k + 1] = (v2f){a.y, c.y};
            Upk[4 * k + 2] = (v2f){a.z, c.z};
            Upk[4 * k + 3] = (v2f){a.w, c.w};
        }
    }
    float kv0 = 0.f, kv1 = 0.f;
    {
        const float4* km = (const float4*)(keys + m * 100);
        const float4* v0 = (const float4*)(V + e0 * 100);
        const float4* v1 = (const float4*)(V + e1 * 100);
        #pragma unroll
        for (int k = 0; k < 25; ++k) {
            float4 kk = km[k], a = v0[k], c = v1[k];
            kv0 += a.x * kk.x + a.y * kk.y + a.z * kk.z + a.w * kk.w;
            kv1 += c.x * kk.x + c.y * kk.y + c.z * kk.z + c.w * kk.w;
        }
    }
    const float k0 = keys[m * 100 + e0];
    const float k1 = h * keys[m * 100 + e1];
    float nm0 = k0, nm1 = k1;        // unnormalized mem; true mem = rn*nm
    memF[lane] = nm0;
    memF[64 + lane] = nm1;
    __asm__ __volatile__("" ::: "memory");

    // nsq = ||mem_0||^2 = ||keys_m||^2 (one-time reduction)
    float nq = k0 * k0 + k1 * k1;
    nq = dpp_add_f<0x111>(nq); nq = dpp_add_f<0x112>(nq); nq = dpp_add_f<0x114>(nq);
    nq = dpp_add_f<0x118>(nq); nq = dpp_add_f<0x142>(nq); nq = dpp_add_f<0x143>(nq);
    float nsq = lane63(nq);
    float rn = 1.f;

    const float* encRow = enc + (size_t)b * 25600;
    const float* sWRow  = sWp + (size_t)b * 25600;
    const float* kgRow  = kg + (size_t)b * 5120 + m;

    float sv0 = encRow[e0], sv1 = encRow[e1];
    float sw0 = sWRow[e0],  sw1 = sWRow[e1];
    float kgc = kgRow[0];

    for (int step = 0; step < 256; ++step) {
        const int nxt = (step < 255 ? step + 1 : 255);
        const float nsv0 = encRow[nxt * 100 + e0], nsv1 = encRow[nxt * 100 + e1];
        const float nsw0 = sWRow[nxt * 100 + e0], nsw1 = sWRow[nxt * 100 + e1];
        const float nkg  = kgRow[nxt * 20];

        // matvec over unnormalized nm, 5 independent accumulator chains
        v2f A0 = {0.f,0.f}, A1 = {0.f,0.f}, A2 = {0.f,0.f}, A3 = {0.f,0.f}, A4 = {0.f,0.f};
        #pragma unroll
        for (int k = 0; k < 25; k += 5) {
            float4 v0 = mem4[k],     v1 = mem4[k + 1], v2 = mem4[k + 2];
            float4 v3 = mem4[k + 3], v4 = mem4[k + 4];
            A0 += Upk[4*k+0]*v0.x;      A0 += Upk[4*k+1]*v0.y;      A0 += Upk[4*k+2]*v0.z;      A0 += Upk[4*k+3]*v0.w;
            A1 += Upk[4*(k+1)+0]*v1.x;  A1 += Upk[4*(k+1)+1]*v1.y;  A1 += Upk[4*(k+1)+2]*v1.z;  A1 += Upk[4*(k+1)+3]*v1.w;
            A2 += Upk[4*(k+2)+0]*v2.x;  A2 += Upk[4*(k+2)+1]*v2.y;  A2 += Upk[4*(k+2)+2]*v2.z;  A2 += Upk[4*(k+2)+3]*v2.w;
            A3 += Upk[4*(k+3)+0]*v3.x;  A3 += Upk[4*(k+3)+1]*v3.y;  A3 += Upk[4*(k+3)+2]*v3.z;  A3 += Upk[4*(k+3)+3]*v3.w;
            A4 += Upk[4*(k+4)+0]*v4.x;  A4 += Upk[4*(k+4)+1]*v4.y;  A4 += Upk[4*(k+4)+2]*v4.z;  A4 += Upk[4*(k+4)+3]*v4.w;
        }
        v2f acc = ((A0 + A1) + (A2 + A3)) + A4;

        // cand = prelu(rn*acc + kV + sW)
        float x0 = rn * acc.x + kv0 + sw0;
        float x1 = rn * acc.y + kv1 + sw1;
        float c0 = (x0 >= 0.f) ? x0 : pa * x0;
        float c1 = (x1 >= 0.f) ? x1 : pa * x1;
        c1 *= h;                                    // mask invalid e1 once

        // 3 fused partials (raw, rn folded in scalar math)
        float q1 = sv0 * nm0 + sv1 * nm1;           // s . nm
        float q3 = nm0 * c0 + nm1 * c1;             // nm . cand
        float p4 = c0 * c0 + c1 * c1;               // cand . cand
        #define RND3(C) q1 = dpp_add_f<C>(q1); q3 = dpp_add_f<C>(q3); p4 = dpp_add_f<C>(p4);
        RND3(0x111) RND3(0x112) RND3(0x114) RND3(0x118) RND3(0x142) RND3(0x143)
        #undef RND3
        const float Q1 = lane63(q1);
        const float Q3 = lane63(q3);
        const float P4 = lane63(p4);

        const float g = 1.f / (1.f + __expf(-(rn * Q1 + kgc)));

        // update unnormalized mem, write to LDS ASAP (normalize stays scalar, off-path)
        nm0 = rn * nm0 + g * c0;
        nm1 = rn * nm1 + g * c1;
        memF[lane] = nm0;
        memF[64 + lane] = nm1;
        __asm__ __volatile__("" ::: "memory");

        const float grn = g * rn;
        const float n2 = nsq + 2.f * grn * Q3 + g * g * P4;   // ||mem + g*cand||^2
        rn = rsqrtf(n2);
        nsq = 1.f;                                  // ||mem||^2 == 1 for all t>=1

        sv0 = nsv0; sv1 = nsv1; sw0 = nsw0; sw1 = nsw1; kgc = nkg;
    }
    float* orow = out + (size_t)(b * 20 + m) * 100;
    orow[e0] = nm0 * rn;
    if (hi) orow[e1] = nm1 * rn;
}

extern "C" void kernel_launch(void* const* d_in, const int* in_sizes, int n_in,
                              void* d_out, int out_size, void* d_ws, size_t ws_size,
                              hipStream_t stream) {
    const float* batch = (const float*)d_in[0];
    const float* encm  = (const float*)d_in[1];
    const float* keys  = (const float*)d_in[2];
    const float* U     = (const float*)d_in[3];
    const float* V     = (const float*)d_in[4];
    const float* W     = (const float*)d_in[5];
    const float* pa    = (const float*)d_in[6];
    float* out = (float*)d_out;

    float* enc = (float*)d_ws;          // 819200 floats
    float* sWp = enc + 819200;          // 819200 floats
    float* kgb = sWp + 819200;          // 163840 floats (total ~7.2 MB)

    encode_k<<<1024, 64, 0, stream>>>(batch, encm, enc);
    project_k<<<2048, 128, 0, stream>>>(enc, W, keys, sWp, kgb);
    entnet_scan<<<640, 64, 0, stream>>>(enc, sWp, kgb, keys, U, V, pa, out);
}

// Round 5
// 529.508 us; speedup vs baseline: 1.0479x; 1.0479x over previous
//
#include <hip/hip_runtime.h>

// EntNet: B=32, S=256, L=64, D=100, M=20
// K1 encode_k : enc[r,:] = sum_l batch[r,l,:]*encm[l,:], pure streaming, 2 acc chains
// K0 prep_k   : T[d][e] = W[e][d] (e<100), keys[e-100][d] (100<=e<120)  -- coalesced project reads
// K2 project_k: sWp[r,e] = enc[r]·W[e,:], kg[r,m] = enc[r]·keys[m,:]  via T + LDS-staged enc
// K3 entnet_scan: 640 chains, 1 wave, zero barriers. P=U·nm register recurrence:
//    Q=U·cand overlaps the DPP reduction; P' = rn*P + g*Q. 3 fused DPP partials,
//    unnormalized mem with wave-uniform rn, kg precomputed.

typedef float v2f __attribute__((ext_vector_type(2)));

__global__ __launch_bounds__(256) void encode_k(
    const float* __restrict__ batch,
    const float* __restrict__ encm,
    float* __restrict__ enc)
{
    const int tid = blockIdx.x * 256 + threadIdx.x;   // 800 blocks -> 204800 = 8192*25
    const int r = tid / 25;
    const int c = tid % 25;
    const float4* b4 = (const float4*)batch + (size_t)r * 1600 + c;
    const float4* e4 = (const float4*)encm + c;
    float4 a0 = {0.f,0.f,0.f,0.f}, a1 = {0.f,0.f,0.f,0.f};
    #pragma unroll 8
    for (int l = 0; l < 64; l += 2) {
        float4 x0 = b4[l * 25],       mu0 = e4[l * 25];
        float4 x1 = b4[(l + 1) * 25], mu1 = e4[(l + 1) * 25];
        a0.x += x0.x * mu0.x; a0.y += x0.y * mu0.y; a0.z += x0.z * mu0.z; a0.w += x0.w * mu0.w;
        a1.x += x1.x * mu1.x; a1.y += x1.y * mu1.y; a1.z += x1.z * mu1.z; a1.w += x1.w * mu1.w;
    }
    float4 s;
    s.x = a0.x + a1.x; s.y = a0.y + a1.y; s.z = a0.z + a1.z; s.w = a0.w + a1.w;
    ((float4*)enc)[(size_t)r * 25 + c] = s;
}

__global__ void prep_k(const float* __restrict__ W,
                       const float* __restrict__ keys,
                       float* __restrict__ T)
{
    const int d = blockIdx.x;          // 100 blocks x 128
    const int e = threadIdx.x;
    float v = 0.f;
    if (e < 100) v = W[e * 100 + d];
    else if (e < 120) v = keys[(e - 100) * 100 + d];
    T[d * 128 + e] = v;
}

__global__ __launch_bounds__(128) void project_k(
    const float* __restrict__ enc,
    const float* __restrict__ T,
    float* __restrict__ sWp,
    float* __restrict__ kg)
{
    __shared__ float encS[400];
    const int t = threadIdx.x;
    const int row0 = blockIdx.x * 4;                  // 2048 blocks -> 8192 rows
    if (t < 100) ((float4*)encS)[t] = ((const float4*)(enc + (size_t)row0 * 100))[t];
    __syncthreads();
    float a0 = 0.f, a1 = 0.f, a2 = 0.f, a3 = 0.f;
    #pragma unroll 4
    for (int d = 0; d < 100; ++d) {
        const float w = T[d * 128 + t];               // coalesced 512B row
        a0 += w * encS[d];
        a1 += w * encS[100 + d];
        a2 += w * encS[200 + d];
        a3 += w * encS[300 + d];
    }
    if (t < 100) {
        sWp[(size_t)row0 * 100 + t]       = a0;
        sWp[(size_t)(row0 + 1) * 100 + t] = a1;
        sWp[(size_t)(row0 + 2) * 100 + t] = a2;
        sWp[(size_t)(row0 + 3) * 100 + t] = a3;
    } else if (t < 120) {
        const int m = t - 100;
        kg[(size_t)row0 * 20 + m]       = a0;
        kg[(size_t)(row0 + 1) * 20 + m] = a1;
        kg[(size_t)(row0 + 2) * 20 + m] = a2;
        kg[(size_t)(row0 + 3) * 20 + m] = a3;
    }
}

template <int CTRL>
__device__ __forceinline__ float dpp_add_f(float x) {
    int s = __builtin_amdgcn_update_dpp(0, __float_as_int(x), CTRL, 0xF, 0xF, true);
    return x + __int_as_float(s);
}
__device__ __forceinline__ float lane63(float x) {
    return __int_as_float(__builtin_amdgcn_readlane(__float_as_int(x), 63));
}

// matvec over LDS-broadcast vector (100 floats) with U rows in registers.
// Macro (not function) so Upk never has its address taken -> stays in VGPRs.
#define MATVEC100(RES, SRC4)                                                   \
    {                                                                          \
        v2f A0 = {0.f,0.f}, A1 = {0.f,0.f}, A2 = {0.f,0.f}, A3 = {0.f,0.f};    \
        _Pragma("unroll")                                                      \
        for (int k = 0; k < 25; ++k) {                                         \
            float4 v = (SRC4)[k];                                              \
            A0 += Upk[4 * k + 0] * v.x;                                        \
            A1 += Upk[4 * k + 1] * v.y;                                        \
            A2 += Upk[4 * k + 2] * v.z;                                        \
            A3 += Upk[4 * k + 3] * v.w;                                        \
        }                                                                      \
        RES = (A0 + A1) + (A2 + A3);                                           \
    }

__global__ __launch_bounds__(64, 1) void entnet_scan(
    const float* __restrict__ enc,    // [8192*100]
    const float* __restrict__ sWp,    // [8192*100]
    const float* __restrict__ kg,     // [8192*20]
    const float* __restrict__ keys,   // [20*100]
    const float* __restrict__ U,      // [100*100]
    const float* __restrict__ V,      // [100*100]
    const float* __restrict__ paPtr,
    float* __restrict__ out)          // [32*20*100]
{
    __shared__ float4 cand4[32];      // 128 floats; [100..127] masked-zero zone
    float* candF = (float*)cand4;
    const int lane = threadIdx.x;
    const int b = blockIdx.x / 20;
    const int m = blockIdx.x % 20;
    const bool hi = (lane < 36);
    const float h = hi ? 1.f : 0.f;
    const int e0 = lane;
    const int e1 = hi ? (64 + lane) : 99;
    const float pa = paPtr[0];

    v2f Upk[100];
    {
        const float4* u0 = (const float4*)(U + e0 * 100);
        const float4* u1 = (const float4*)(U + e1 * 100);
        #pragma unroll
        for (int k = 0; k < 25; ++k) {
            float4 a = u0[k], c = u1[k];
            Upk[4 * k + 0] = (v2f){a.x, c.x};
            Upk[4 * k + 1] = (v2f){a.y, c.y};
            Upk[4 * k + 2] = (v2f){a.z, c.z};
            Upk[4 * k + 3] = (v2f){a.w, c.w};
        }
    }
    float kv0 = 0.f, kv1 = 0.f;
    {
        const float4* km = (const float4*)(keys + m * 100);
        const float4* v0 = (const float4*)(V + e0 * 100);
        const float4* v1 = (const float4*)(V + e1 * 100);
        #pragma unroll
        for (int k = 0; k < 25; ++k) {
            float4 kk = km[k], a = v0[k], c = v1[k];
            kv0 += a.x * kk.x + a.y * kk.y + a.z * kk.z + a.w * kk.w;
            kv1 += c.x * kk.x + c.y * kk.y + c.z * kk.z + c.w * kk.w;
        }
    }
    const float k0 = keys[m * 100 + e0];
    const float k1 = h * keys[m * 100 + e1];
    float nm0 = k0, nm1 = k1;        // unnormalized mem; true mem = rn*nm
    candF[lane] = nm0;
    candF[64 + lane] = nm1;
    __asm__ __volatile__("" ::: "memory");

    v2f P;                            // P = U . nm (register recurrence)
    MATVEC100(P, cand4);

    float nq = k0 * k0 + k1 * k1;     // ||mem_0||^2
    nq = dpp_add_f<0x111>(nq); nq = dpp_add_f<0x112>(nq); nq = dpp_add_f<0x114>(nq);
    nq = dpp_add_f<0x118>(nq); nq = dpp_add_f<0x142>(nq); nq = dpp_add_f<0x143>(nq);
    float nsq = lane63(nq);
    float rn = 1.f;

    const float* encRow = enc + (size_t)b * 25600;
    const float* sWRow  = sWp + (size_t)b * 25600;
    const float* kgRow  = kg + (size_t)b * 5120 + m;

    float sv0 = encRow[e0], sv1 = encRow[e1];
    float sw0 = sWRow[e0],  sw1 = sWRow[e1];
    float kgc = kgRow[0];

    for (int step = 0; step < 256; ++step) {
        const int nxt = (step < 255 ? step + 1 : 255);
        const float nsv0 = encRow[nxt * 100 + e0], nsv1 = encRow[nxt * 100 + e1];
        const float nsw0 = sWRow[nxt * 100 + e0], nsw1 = sWRow[nxt * 100 + e1];
        const float nkg  = kgRow[nxt * 20];

        // cand directly from P (no LDS matvec on this path)
        const float x0 = rn * P.x + kv0 + sw0;
        const float x1 = rn * P.y + kv1 + sw1;
        float c0 = (x0 >= 0.f) ? x0 : pa * x0;
        float c1 = (x1 >= 0.f) ? x1 : pa * x1;
        c1 *= h;

        // publish cand for the Q matvec
        candF[lane] = c0;
        candF[64 + lane] = c1;
        __asm__ __volatile__("" ::: "memory");

        // 3 fused partials (raw nm; rn folded scalar-side)
        float q1 = sv0 * nm0 + sv1 * nm1;           // s . nm
        float q3 = nm0 * c0 + nm1 * c1;             // nm . cand
        float p4 = c0 * c0 + c1 * c1;               // cand . cand
        #define RND3(C) q1 = dpp_add_f<C>(q1); q3 = dpp_add_f<C>(q3); p4 = dpp_add_f<C>(p4);
        RND3(0x111) RND3(0x112) RND3(0x114) RND3(0x118) RND3(0x142) RND3(0x143)
        #undef RND3

        // Q = U . cand — issues while DPP chain settles
        v2f Q;
        MATVEC100(Q, cand4);

        const float Q1 = lane63(q1);
        const float Q3 = lane63(q3);
        const float P4 = lane63(p4);

        const float g = 1.f / (1.f + __expf(-(rn * Q1 + kgc)));

        nm0 = rn * nm0 + g * c0;
        nm1 = rn * nm1 + g * c1;
        P = rn * P + g * Q;                          // U.nm recurrence

        const float n2 = nsq + 2.f * (g * rn) * Q3 + g * g * P4;
        rn = rsqrtf(n2);
        nsq = 1.f;

        sv0 = nsv0; sv1 = nsv1; sw0 = nsw0; sw1 = nsw1; kgc = nkg;
    }
    float* orow = out + (size_t)(b * 20 + m) * 100;
    orow[e0] = nm0 * rn;
    if (hi) orow[e1] = nm1 * rn;
}

extern "C" void kernel_launch(void* const* d_in, const int* in_sizes, int n_in,
                              void* d_out, int out_size, void* d_ws, size_t ws_size,
                              hipStream_t stream) {
    const float* batch = (const float*)d_in[0];
    const float* encm  = (const float*)d_in[1];
    const float* keys  = (const float*)d_in[2];
    const float* U     = (const float*)d_in[3];
    const float* V     = (const float*)d_in[4];
    const float* W     = (const float*)d_in[5];
    const float* pa    = (const float*)d_in[6];
    float* out = (float*)d_out;

    float* enc = (float*)d_ws;          // 819200 floats
    float* sWp = enc + 819200;          // 819200 floats
    float* kgb = sWp + 819200;          // 163840 floats
    float* T   = kgb + 163840;          // 12800 floats (~7.27 MB total)

    encode_k<<<800, 256, 0, stream>>>(batch, encm, enc);
    prep_k<<<100, 128, 0, stream>>>(W, keys, T);
    project_k<<<2048, 128, 0, stream>>>(enc, T, sWp, kgb);
    entnet_scan<<<640, 64, 0, stream>>>(enc, sWp, kgb, keys, U, V, pa, out);
}

// Round 6
// 515.614 us; speedup vs baseline: 1.0762x; 1.0269x over previous
//
#include <hip/hip_runtime.h>

// EntNet: B=32, S=256, L=64, D=100, M=20
// K1 encode_k : one row/block, fully contiguous float4 streaming -> LDS product stage ->
//               conflict-free column reduce -> enc[8192,100]
// K0 prep_k   : T[d][e] = W[e][d] (e<100), keys[e-100][d] (100<=e<120)
// K2 project_k: sWp[r,e] = enc[r]·W[e,:], kg[r,m] = enc[r]·keys[m,:]  via T + LDS-staged enc
// K3 entnet_scan: 640 chains, 1 wave, zero barriers, software-pipelined gate:
//    g_{t} computed in step t-1's tail (overlaps next matvec); rn' computed under matvec.
//    Critical path/step = x -> prelu -> ds_write -> 25 broadcast ds_read -> 100 pk_fma -> P'.

typedef float v2f __attribute__((ext_vector_type(2)));

__global__ __launch_bounds__(320) void encode_k(
    const float* __restrict__ batch,
    const float* __restrict__ encm,
    float* __restrict__ enc)
{
    __shared__ float prod[6400];      // 25.6 KB: one row of products
    __shared__ float part[200];
    const int t = threadIdx.x;
    const int row = blockIdx.x;       // 8192 blocks
    const float4* rb = (const float4*)batch + (size_t)row * 1600;
    const float4* e4 = (const float4*)encm;
    float4* p4 = (float4*)prod;
    #pragma unroll
    for (int i = 0; i < 5; ++i) {     // 320 lanes x 16B = 5 KB contiguous per iter
        const int idx = i * 320 + t;
        float4 x = rb[idx];
        float4 mu = e4[idx];
        float4 p;
        p.x = x.x * mu.x; p.y = x.y * mu.y; p.z = x.z * mu.z; p.w = x.w * mu.w;
        p4[idx] = p;
    }
    __syncthreads();
    if (t < 200) {
        const int c = (t < 100) ? t : (t - 100);
        const int l0 = (t < 100) ? 0 : 32;
        float s0 = 0.f, s1 = 0.f;
        #pragma unroll
        for (int l = 0; l < 32; l += 2) {      // consecutive lanes -> consecutive addrs
            s0 += prod[(l0 + l) * 100 + c];
            s1 += prod[(l0 + l + 1) * 100 + c];
        }
        part[t] = s0 + s1;
    }
    __syncthreads();
    if (t < 100) enc[(size_t)row * 100 + t] = part[t] + part[100 + t];
}

__global__ void prep_k(const float* __restrict__ W,
                       const float* __restrict__ keys,
                       float* __restrict__ T)
{
    const int d = blockIdx.x;          // 100 blocks x 128
    const int e = threadIdx.x;
    float v = 0.f;
    if (e < 100) v = W[e * 100 + d];
    else if (e < 120) v = keys[(e - 100) * 100 + d];
    T[d * 128 + e] = v;
}

__global__ __launch_bounds__(128) void project_k(
    const float* __restrict__ enc,
    const float* __restrict__ T,
    float* __restrict__ sWp,
    float* __restrict__ kg)
{
    __shared__ float encS[400];
    const int t = threadIdx.x;
    const int row0 = blockIdx.x * 4;                  // 2048 blocks -> 8192 rows
    if (t < 100) ((float4*)encS)[t] = ((const float4*)(enc + (size_t)row0 * 100))[t];
    __syncthreads();
    float a0 = 0.f, a1 = 0.f, a2 = 0.f, a3 = 0.f;
    #pragma unroll 4
    for (int d = 0; d < 100; ++d) {
        const float w = T[d * 128 + t];               // coalesced 512B row
        a0 += w * encS[d];
        a1 += w * encS[100 + d];
        a2 += w * encS[200 + d];
        a3 += w * encS[300 + d];
    }
    if (t < 100) {
        sWp[(size_t)row0 * 100 + t]       = a0;
        sWp[(size_t)(row0 + 1) * 100 + t] = a1;
        sWp[(size_t)(row0 + 2) * 100 + t] = a2;
        sWp[(size_t)(row0 + 3) * 100 + t] = a3;
    } else if (t < 120) {
        const int m = t - 100;
        kg[(size_t)row0 * 20 + m]       = a0;
        kg[(size_t)(row0 + 1) * 20 + m] = a1;
        kg[(size_t)(row0 + 2) * 20 + m] = a2;
        kg[(size_t)(row0 + 3) * 20 + m] = a3;
    }
}

template <int CTRL>
__device__ __forceinline__ float dpp_add_f(float x) {
    int s = __builtin_amdgcn_update_dpp(0, __float_as_int(x), CTRL, 0xF, 0xF, true);
    return x + __int_as_float(s);
}
__device__ __forceinline__ float lane63(float x) {
    return __int_as_float(__builtin_amdgcn_readlane(__float_as_int(x), 63));
}
#define DPP6(v) v = dpp_add_f<0x111>(v); v = dpp_add_f<0x112>(v); v = dpp_add_f<0x114>(v); \
                v = dpp_add_f<0x118>(v); v = dpp_add_f<0x142>(v); v = dpp_add_f<0x143>(v);

// matvec over LDS-broadcast vector (100 floats) with U rows in registers.
#define MATVEC100(RES, SRC4)                                                   \
    {                                                                          \
        v2f A0 = {0.f,0.f}, A1 = {0.f,0.f}, A2 = {0.f,0.f}, A3 = {0.f,0.f};    \
        _Pragma("unroll")                                                      \
        for (int k = 0; k < 25; ++k) {                                         \
            float4 v = (SRC4)[k];                                              \
            A0 += Upk[4 * k + 0] * v.x;                                        \
            A1 += Upk[4 * k + 1] * v.y;                                        \
            A2 += Upk[4 * k + 2] * v.z;                                        \
            A3 += Upk[4 * k + 3] * v.w;                                        \
        }                                                                      \
        RES = (A0 + A1) + (A2 + A3);                                           \
    }

__global__ __attribute__((amdgpu_waves_per_eu(1, 1))) __launch_bounds__(64)
void entnet_scan(
    const float* __restrict__ enc,    // [8192*100]
    const float* __restrict__ sWp,    // [8192*100]
    const float* __restrict__ kg,     // [8192*20]
    const float* __restrict__ keys,   // [20*100]
    const float* __restrict__ U,      // [100*100]
    const float* __restrict__ V,      // [100*100]
    const float* __restrict__ paPtr,
    float* __restrict__ out)          // [32*20*100]
{
    __shared__ float4 cand4[32];      // 128 floats; [100..127] = always-zero pad zone
    float* candF = (float*)cand4;
    const int lane = threadIdx.x;
    const int b = blockIdx.x / 20;
    const int m = blockIdx.x % 20;
    const bool hi = (lane < 36);
    const float h = hi ? 1.f : 0.f;
    const int e0 = lane;
    const int e1 = hi ? (64 + lane) : 99;
    const float pa = paPtr[0];

    v2f Upk[100];
    {
        const float4* u0 = (const float4*)(U + e0 * 100);
        const float4* u1 = (const float4*)(U + e1 * 100);
        #pragma unroll
        for (int k = 0; k < 25; ++k) {
            float4 a = u0[k], c = u1[k];
            Upk[4 * k + 0] = (v2f){a.x, c.x};
            Upk[4 * k + 1] = (v2f){a.y, c.y};
            Upk[4 * k + 2] = (v2f){a.z, c.z};
            Upk[4 * k + 3] = (v2f){a.w, c.w};
        }
    }
    float kv0 = 0.f, kv1 = 0.f;
    {
        const float4* km = (const float4*)(keys + m * 100);
        const float4* v0 = (const float4*)(V + e0 * 100);
        const float4* v1 = (const float4*)(V + e1 * 100);
        #pragma unroll
        for (int k = 0; k < 25; ++k) {
            float4 kk = km[k], a = v0[k], c = v1[k];
            kv0 += a.x * kk.x + a.y * kk.y + a.z * kk.z + a.w * kk.w;
            kv1 += c.x * kk.x + c.y * kk.y + c.z * kk.z + c.w * kk.w;
        }
    }
    const float k0 = keys[m * 100 + e0];
    const float k1 = h * keys[m * 100 + e1];
    float nm0 = k0, nm1 = k1;        // unnormalized mem; true mem = rn*nm
    candF[lane] = nm0;
    candF[64 + lane] = nm1;
    __asm__ __volatile__("" ::: "memory");

    v2f P;                            // P = U . nm (register recurrence)
    MATVEC100(P, cand4);

    float nq = k0 * k0 + k1 * k1;     // ||mem_0||^2
    DPP6(nq)
    float nsq = lane63(nq);
    float rn = 1.f;

    const float* encRow = enc + (size_t)b * 25600;
    const float* sWRow  = sWp + (size_t)b * 25600;
    const float* kgRow  = kg + (size_t)b * 5120 + m;

    float sw0 = sWRow[e0], sw1 = sWRow[e1];
    // gate for step 0 (pipelined pattern primed outside the loop)
    float g;
    {
        const float sv0 = encRow[e0], sv1 = encRow[e1];
        const float kg0 = kgRow[0];
        float q1 = sv0 * nm0 + sv1 * nm1;
        DPP6(q1)
        const float Q1 = lane63(q1);
        g = 1.f / (1.f + __expf(-(Q1 + kg0)));   // rn == 1 at t=0
    }

    for (int step = 0; step < 256; ++step) {
        const int nxt = (step < 255 ? step + 1 : 255);
        const float nsv0 = encRow[nxt * 100 + e0], nsv1 = encRow[nxt * 100 + e1];
        const float nsw0 = sWRow[nxt * 100 + e0], nsw1 = sWRow[nxt * 100 + e1];
        const float nkg  = kgRow[nxt * 20];

        // ---- critical path: x -> cand -> LDS -> matvec ----
        const float x0 = rn * P.x + kv0 + sw0;
        const float x1 = rn * P.y + kv1 + sw1;
        float c0 = (x0 >= 0.f) ? x0 : pa * x0;
        float c1 = (x1 >= 0.f) ? x1 : pa * x1;
        c1 *= h;
        candF[lane] = c0;
        candF[64 + lane] = c1;
        __asm__ __volatile__("" ::: "memory");

        // off-path: norm partials reduce under the matvec
        float q3 = nm0 * c0 + nm1 * c1;             // nm . cand
        float p4 = c0 * c0 + c1 * c1;               // cand . cand
        #define RND2(C) q3 = dpp_add_f<C>(q3); p4 = dpp_add_f<C>(p4);
        RND2(0x111) RND2(0x112) RND2(0x114) RND2(0x118) RND2(0x142) RND2(0x143)
        #undef RND2

        v2f Q;
        MATVEC100(Q, cand4);

        const float Q3 = lane63(q3);
        const float P4 = lane63(p4);
        const float n2 = nsq + 2.f * (g * rn) * Q3 + g * g * P4;
        const float rnn = rsqrtf(n2);               // rn_{t+1}, off the matvec path
        nsq = 1.f;

        // state update (path: needs Q and precomputed g)
        nm0 = rn * nm0 + g * c0;
        nm1 = rn * nm1 + g * c1;
        P = rn * P + g * Q;

        // tail (overlaps next step's matvec): gate for step t+1
        float q1 = nsv0 * nm0 + nsv1 * nm1;
        DPP6(q1)
        const float Q1 = lane63(q1);
        g = 1.f / (1.f + __expf(-(rnn * Q1 + nkg)));

        rn = rnn;
        sw0 = nsw0; sw1 = nsw1;
    }
    const float* dummy = V;  (void)dummy;
    float* orow = out + (size_t)(b * 20 + m) * 100;
    orow[e0] = nm0 * rn;
    if (hi) orow[e1] = nm1 * rn;
}

extern "C" void kernel_launch(void* const* d_in, const int* in_sizes, int n_in,
                              void* d_out, int out_size, void* d_ws, size_t ws_size,
                              hipStream_t stream) {
    const float* batch = (const float*)d_in[0];
    const float* encm  = (const float*)d_in[1];
    const float* keys  = (const float*)d_in[2];
    const float* U     = (const float*)d_in[3];
    const float* V     = (const float*)d_in[4];
    const float* W     = (const float*)d_in[5];
    const float* pa    = (const float*)d_in[6];
    float* out = (float*)d_out;

    float* enc = (float*)d_ws;          // 819200 floats
    float* sWp = enc + 819200;          // 819200 floats
    float* kgb = sWp + 819200;          // 163840 floats
    float* T   = kgb + 163840;          // 12800 floats (~7.27 MB total)

    encode_k<<<8192, 320, 0, stream>>>(batch, encm, enc);
    prep_k<<<100, 128, 0, stream>>>(W, keys, T);
    project_k<<<2048, 128, 0, stream>>>(enc, T, sWp, kgb);
    entnet_scan<<<640, 64, 0, stream>>>(enc, sWp, kgb, keys, U, V, pa, out);
}

// Round 7
// 512.105 us; speedup vs baseline: 1.0835x; 1.0069x over previous
//
#include <hip/hip_runtime.h>

// EntNet: B=32, S=256, L=64, D=100, M=20
// K1 encode_k : one row/block contiguous streaming -> LDS stage -> column reduce
// K0 prep_k   : T[d][e] = W[e][d] / keys
// K2 project_k: sWp = enc·W^T, kg = enc·keys^T via T
// K3 entnet_scan: 640 chains, 1 wave, ZERO LDS in loop: cand broadcast via v_readlane
//    (SGPR) into v_fmac chains; XCD-swizzled so each XCD holds 4 b-slices in L2.

typedef float v2f __attribute__((ext_vector_type(2)));

__global__ __launch_bounds__(320) void encode_k(
    const float* __restrict__ batch,
    const float* __restrict__ encm,
    float* __restrict__ enc)
{
    __shared__ float prod[6400];
    __shared__ float part[200];
    const int t = threadIdx.x;
    const int row = blockIdx.x;       // 8192 blocks
    const float4* rb = (const float4*)batch + (size_t)row * 1600;
    const float4* e4 = (const float4*)encm;
    float4* p4 = (float4*)prod;
    #pragma unroll
    for (int i = 0; i < 5; ++i) {
        const int idx = i * 320 + t;
        float4 x = rb[idx];
        float4 mu = e4[idx];
        float4 p;
        p.x = x.x * mu.x; p.y = x.y * mu.y; p.z = x.z * mu.z; p.w = x.w * mu.w;
        p4[idx] = p;
    }
    __syncthreads();
    if (t < 200) {
        const int c = (t < 100) ? t : (t - 100);
        const int l0 = (t < 100) ? 0 : 32;
        float s0 = 0.f, s1 = 0.f;
        #pragma unroll
        for (int l = 0; l < 32; l += 2) {
            s0 += prod[(l0 + l) * 100 + c];
            s1 += prod[(l0 + l + 1) * 100 + c];
        }
        part[t] = s0 + s1;
    }
    __syncthreads();
    if (t < 100) enc[(size_t)row * 100 + t] = part[t] + part[100 + t];
}

__global__ void prep_k(const float* __restrict__ W,
                       const float* __restrict__ keys,
                       float* __restrict__ T)
{
    const int d = blockIdx.x;
    const int e = threadIdx.x;
    float v = 0.f;
    if (e < 100) v = W[e * 100 + d];
    else if (e < 120) v = keys[(e - 100) * 100 + d];
    T[d * 128 + e] = v;
}

__global__ __launch_bounds__(128) void project_k(
    const float* __restrict__ enc,
    const float* __restrict__ T,
    float* __restrict__ sWp,
    float* __restrict__ kg)
{
    __shared__ float encS[400];
    const int t = threadIdx.x;
    const int row0 = blockIdx.x * 4;
    if (t < 100) ((float4*)encS)[t] = ((const float4*)(enc + (size_t)row0 * 100))[t];
    __syncthreads();
    float a0 = 0.f, a1 = 0.f, a2 = 0.f, a3 = 0.f;
    #pragma unroll 4
    for (int d = 0; d < 100; ++d) {
        const float w = T[d * 128 + t];
        a0 += w * encS[d];
        a1 += w * encS[100 + d];
        a2 += w * encS[200 + d];
        a3 += w * encS[300 + d];
    }
    if (t < 100) {
        sWp[(size_t)row0 * 100 + t]       = a0;
        sWp[(size_t)(row0 + 1) * 100 + t] = a1;
        sWp[(size_t)(row0 + 2) * 100 + t] = a2;
        sWp[(size_t)(row0 + 3) * 100 + t] = a3;
    } else if (t < 120) {
        const int m = t - 100;
        kg[(size_t)row0 * 20 + m]       = a0;
        kg[(size_t)(row0 + 1) * 20 + m] = a1;
        kg[(size_t)(row0 + 2) * 20 + m] = a2;
        kg[(size_t)(row0 + 3) * 20 + m] = a3;
    }
}

template <int CTRL>
__device__ __forceinline__ float dpp_add_f(float x) {
    int s = __builtin_amdgcn_update_dpp(0, __float_as_int(x), CTRL, 0xF, 0xF, true);
    return x + __int_as_float(s);
}
__device__ __forceinline__ float lane63(float x) {
    return __int_as_float(__builtin_amdgcn_readlane(__float_as_int(x), 63));
}
template <int L>
__device__ __forceinline__ float bcast(float x) {
    return __int_as_float(__builtin_amdgcn_readlane(__float_as_int(x), L));
}
#define DPP6(v) v = dpp_add_f<0x111>(v); v = dpp_add_f<0x112>(v); v = dpp_add_f<0x114>(v); \
                v = dpp_add_f<0x118>(v); v = dpp_add_f<0x142>(v); v = dpp_add_f<0x143>(v);

// LDS-free matvec: RES(v2f) = U[e0/e1,:] . cand, cand broadcast via readlane.
// S0 holds cand[0..63] (lane k), S1 holds cand[64..99] (lane k-64).
#define MVSTEP(A, k, ck) { float c_ = (ck); A.x = __builtin_fmaf(U0[k], c_, A.x); \
                                            A.y = __builtin_fmaf(U1[k], c_, A.y); }
#define MATVECRL(RES, S0, S1)                                                  \
    {                                                                          \
        v2f A0 = {0.f,0.f}, A1 = {0.f,0.f}, A2 = {0.f,0.f}, A3 = {0.f,0.f};    \
        mv_unroll64(A0, A1, A2, A3, S0);                                       \
        mv_unroll36(A0, A1, A2, A3, S1);                                       \
        RES = (A0 + A1) + (A2 + A3);                                           \
    }

__global__ __attribute__((amdgpu_waves_per_eu(1, 1))) __launch_bounds__(64)
void entnet_scan(
    const float* __restrict__ enc,    // [8192*100]
    const float* __restrict__ sWp,    // [8192*100]
    const float* __restrict__ kg,     // [8192*20]
    const float* __restrict__ keys,   // [20*100]
    const float* __restrict__ U,      // [100*100]
    const float* __restrict__ V,      // [100*100]
    const float* __restrict__ paPtr,
    float* __restrict__ out)          // [32*20*100]
{
    const int lane = threadIdx.x;
    // XCD swizzle: XCD = blockIdx%8 serves b in {4*xcd .. 4*xcd+3}
    const int xcd = blockIdx.x & 7;
    const int gg  = blockIdx.x >> 3;          // 0..79
    const int b = xcd * 4 + gg / 20;
    const int m = gg % 20;
    const bool hi = (lane < 36);
    const float h = hi ? 1.f : 0.f;
    const int e0 = lane;
    const int e1 = hi ? (64 + lane) : 99;
    const float pa = paPtr[0];

    float U0[100], U1[100];
    {
        const float4* u0 = (const float4*)(U + e0 * 100);
        const float4* u1 = (const float4*)(U + e1 * 100);
        #pragma unroll
        for (int k = 0; k < 25; ++k) {
            float4 a = u0[k], c = u1[k];
            U0[4*k] = a.x; U0[4*k+1] = a.y; U0[4*k+2] = a.z; U0[4*k+3] = a.w;
            U1[4*k] = c.x; U1[4*k+1] = c.y; U1[4*k+2] = c.z; U1[4*k+3] = c.w;
        }
    }
    auto mv_unroll64 = [&](v2f& A0, v2f& A1, v2f& A2, v2f& A3, float S0) {
        #define Q4(base) MVSTEP(A0, base+0, bcast<base+0>(S0)) \
                         MVSTEP(A1, base+1, bcast<base+1>(S0)) \
                         MVSTEP(A2, base+2, bcast<base+2>(S0)) \
                         MVSTEP(A3, base+3, bcast<base+3>(S0))
        Q4(0) Q4(4) Q4(8) Q4(12) Q4(16) Q4(20) Q4(24) Q4(28)
        Q4(32) Q4(36) Q4(40) Q4(44) Q4(48) Q4(52) Q4(56) Q4(60)
        #undef Q4
    };
    auto mv_unroll36 = [&](v2f& A0, v2f& A1, v2f& A2, v2f& A3, float S1) {
        #define Q4(base) MVSTEP(A0, 64+base+0, bcast<base+0>(S1)) \
                         MVSTEP(A1, 64+base+1, bcast<base+1>(S1)) \
                         MVSTEP(A2, 64+base+2, bcast<base+2>(S1)) \
                         MVSTEP(A3, 64+base+3, bcast<base+3>(S1))
        Q4(0) Q4(4) Q4(8) Q4(12) Q4(16) Q4(20) Q4(24) Q4(28)
        MVSTEP(A0, 96, bcast<32>(S1)) MVSTEP(A1, 97, bcast<33>(S1))
        MVSTEP(A2, 98, bcast<34>(S1)) MVSTEP(A3, 99, bcast<35>(S1))
        #undef Q4
    };

    float kv0 = 0.f, kv1 = 0.f;
    {
        const float4* km = (const float4*)(keys + m * 100);
        const float4* v0 = (const float4*)(V + e0 * 100);
        const float4* v1 = (const float4*)(V + e1 * 100);
        #pragma unroll
        for (int k = 0; k < 25; ++k) {
            float4 kk = km[k], a = v0[k], c = v1[k];
            kv0 += a.x * kk.x + a.y * kk.y + a.z * kk.z + a.w * kk.w;
            kv1 += c.x * kk.x + c.y * kk.y + c.z * kk.z + c.w * kk.w;
        }
    }
    const float k0 = keys[m * 100 + e0];
    const float k1 = h * keys[m * 100 + e1];
    float nm0 = k0, nm1 = k1;        // unnormalized mem; true mem = rn*nm

    v2f P;                            // P = U . nm (register recurrence)
    MATVECRL(P, nm0, nm1);

    float nq = k0 * k0 + k1 * k1;     // ||mem_0||^2
    DPP6(nq)
    float nsq = lane63(nq);
    float rn = 1.f;

    const float* encRow = enc + (size_t)b * 25600;
    const float* sWRow  = sWp + (size_t)b * 25600;
    const float* kgRow  = kg + (size_t)b * 5120 + m;

    float sw0 = sWRow[e0], sw1 = sWRow[e1];
    float g;
    {
        const float sv0 = encRow[e0], sv1 = encRow[e1];
        const float kg0 = kgRow[0];
        float q1 = sv0 * nm0 + sv1 * nm1;
        DPP6(q1)
        const float Q1 = lane63(q1);
        g = 1.f / (1.f + __expf(-(Q1 + kg0)));   // rn == 1 at t=0
    }

    for (int step = 0; step < 256; ++step) {
        const int nxt = (step < 255 ? step + 1 : 255);
        const float nsv0 = encRow[nxt * 100 + e0], nsv1 = encRow[nxt * 100 + e1];
        const float nsw0 = sWRow[nxt * 100 + e0], nsw1 = sWRow[nxt * 100 + e1];
        const float nkg  = kgRow[nxt * 20];

        // critical path: P -> x -> cand -> readlane matvec -> P'
        const float x0 = rn * P.x + kv0 + sw0;
        const float x1 = rn * P.y + kv1 + sw1;
        float c0 = (x0 >= 0.f) ? x0 : pa * x0;
        float c1 = (x1 >= 0.f) ? x1 : pa * x1;
        c1 *= h;

        // off-path norm partials (overlap matvec issue)
        float q3 = nm0 * c0 + nm1 * c1;             // nm . cand
        float p4 = c0 * c0 + c1 * c1;               // cand . cand
        #define RND2(C) q3 = dpp_add_f<C>(q3); p4 = dpp_add_f<C>(p4);
        RND2(0x111) RND2(0x112) RND2(0x114) RND2(0x118) RND2(0x142) RND2(0x143)
        #undef RND2

        v2f Q;
        MATVECRL(Q, c0, c1);

        const float Q3 = lane63(q3);
        const float P4 = lane63(p4);
        const float n2 = nsq + 2.f * (g * rn) * Q3 + g * g * P4;
        const float rnn = rsqrtf(n2);               // rn_{t+1}
        nsq = 1.f;

        nm0 = rn * nm0 + g * c0;
        nm1 = rn * nm1 + g * c1;
        P = rn * P + g * Q;

        // gate for step t+1 (overlaps next iteration's front)
        float q1 = nsv0 * nm0 + nsv1 * nm1;
        DPP6(q1)
        const float Q1 = lane63(q1);
        g = 1.f / (1.f + __expf(-(rnn * Q1 + nkg)));

        rn = rnn;
        sw0 = nsw0; sw1 = nsw1;
    }
    float* orow = out + (size_t)(b * 20 + m) * 100;
    orow[e0] = nm0 * rn;
    if (hi) orow[e1] = nm1 * rn;
}

extern "C" void kernel_launch(void* const* d_in, const int* in_sizes, int n_in,
                              void* d_out, int out_size, void* d_ws, size_t ws_size,
                              hipStream_t stream) {
    const float* batch = (const float*)d_in[0];
    const float* encm  = (const float*)d_in[1];
    const float* keys  = (const float*)d_in[2];
    const float* U     = (const float*)d_in[3];
    const float* V     = (const float*)d_in[4];
    const float* W     = (const float*)d_in[5];
    const float* pa    = (const float*)d_in[6];
    float* out = (float*)d_out;

    float* enc = (float*)d_ws;          // 819200 floats
    float* sWp = enc + 819200;          // 819200 floats
    float* kgb = sWp + 819200;          // 163840 floats
    float* T   = kgb + 163840;          // 12800 floats

    encode_k<<<8192, 320, 0, stream>>>(batch, encm, enc);
    prep_k<<<100, 128, 0, stream>>>(W, keys, T);
    project_k<<<2048, 128, 0, stream>>>(enc, T, sWp, kgb);
    entnet_scan<<<640, 64, 0, stream>>>(enc, sWp, kgb, keys, U, V, pa, out);
}